// Round 15
// baseline (285.488 us; speedup 1.0000x reference)
//
#include <hip/hip_runtime.h>
#include <cstdint>
#include <cstddef>

typedef _Float16 f16;
typedef __attribute__((ext_vector_type(4)))  _Float16 f16x4;
typedef __attribute__((ext_vector_type(8)))  _Float16 f16x8;
typedef __attribute__((ext_vector_type(2)))  __fp16   fp16v2;
typedef __attribute__((ext_vector_type(4)))  float    f32x4;
typedef __attribute__((ext_vector_type(16))) float    f32x16;

static constexpr int BB = 16, LL = 2048, DIN = 512, HH = 256, DOUT = 1024;
static constexpr float SCALE = 0.0625f;   // 1/sqrt(256)
#define MASKVAL (-30000.0f)               // f16-representable; exp(-30000-M)=0 exactly

#define BAR()    __builtin_amdgcn_s_barrier()
#define SCHED0() __builtin_amdgcn_sched_barrier(0)

__device__ __forceinline__ void gload16(const void* g, void* l) {
  __builtin_amdgcn_global_load_lds(
      (const __attribute__((address_space(1))) unsigned int*)g,
      (__attribute__((address_space(3))) unsigned int*)l, 16, 0, 0);
}

__device__ __forceinline__ unsigned pk2(float a, float b) {
  union { fp16v2 v; unsigned u; } c;
  c.v = __builtin_amdgcn_cvt_pkrtz(a, b);
  return c.u;
}

// ---- both W transposes in one launch: W[512][256] f32 -> WT[256][512] f16
__global__ void wt2_kernel(const float* __restrict__ Wa, const float* __restrict__ Wb,
                           f16* __restrict__ WTa, f16* __restrict__ WTb) {
  int g = blockIdx.x * 256 + threadIdx.x;     // 262144 total
  const float* W = (g < 131072) ? Wa : Wb;
  f16* WT = (g < 131072) ? WTa : WTb;
  int gg = g & 131071;
  int d = gg >> 8, h = gg & 255;
  WT[h * 512 + d] = (f16)W[gg];
}

// ---- V transpose+cast: mem[b][m][512] f32 -> VT[b][512][2048] f16
__global__ void vt_kernel(const float* __restrict__ mem, f16* __restrict__ VT) {
  int m0 = blockIdx.x * 32, d0 = blockIdx.y * 32, b = blockIdx.z;
  __shared__ f16 t[32][36];
  int tid = threadIdx.x;
  {
    int r = tid >> 3, c4 = (tid & 7) * 4;
    float4 v = *(const float4*)(mem + (size_t)(b * LL + m0 + r) * DIN + d0 + c4);
    t[c4 + 0][r] = (f16)v.x; t[c4 + 1][r] = (f16)v.y;
    t[c4 + 2][r] = (f16)v.z; t[c4 + 3][r] = (f16)v.w;
  }
  __syncthreads();
  {
    int d = tid >> 3, seg = tid & 7;
    f16x4 hv = *(const f16x4*)&t[d][seg * 4];
    *(f16x4*)(VT + (size_t)(b * 512 + d0 + d) * 2048 + m0 + seg * 4) = hv;
  }
}

// ---- projection (both in one launch): Out[M][256] = f16(relu(X * W))
__global__ __launch_bounds__(256, 2) void proj_kernel(const float* __restrict__ Xa,
                                                      const float* __restrict__ Xb,
                                                      const f16* __restrict__ WTa,
                                                      const f16* __restrict__ WTb,
                                                      f16* __restrict__ Oa,
                                                      f16* __restrict__ Ob) {
  const float* X = blockIdx.z ? Xb : Xa;
  const f16* WT  = blockIdx.z ? WTb : WTa;
  f16* Out       = blockIdx.z ? Ob : Oa;
  const int Rbase = blockIdx.x * 128, Cbase = blockIdx.y * 128;
  __shared__ f16 a_t[128 * 40];
  __shared__ f16 b_t[128 * 32];
  const int tid = threadIdx.x, lane = tid & 63, wave = tid >> 6;
  const int wr = wave >> 1, wc = wave & 1;
  const int l15 = lane & 15, g4 = lane >> 4;
  f32x4 acc[4][4] = {};
  for (int ks = 0; ks < 16; ++ks) {
    __syncthreads();
#pragma unroll
    for (int k = 0; k < 4; ++k) {
      int idx = k * 256 + tid;
      int row = idx >> 3, c4 = idx & 7;
      float4 v = *(const float4*)(X + (size_t)(Rbase + row) * 512 + ks * 32 + c4 * 4);
      f16x4 hv = { (f16)v.x, (f16)v.y, (f16)v.z, (f16)v.w };
      *(f16x4*)((char*)a_t + row * 80 + c4 * 8) = hv;
    }
#pragma unroll
    for (int i = 0; i < 2; ++i) {
      int o = i * 4096 + wave * 1024 + lane * 16;
      int r = o >> 6, cp = o & 63;
      gload16((const char*)WT + (size_t)(Cbase + r) * 1024 + ks * 64 + (cp ^ ((r & 3) << 4)),
              (char*)b_t + i * 4096 + wave * 1024);
    }
    __syncthreads();
    f16x8 af[4], bf[4];
#pragma unroll
    for (int mi = 0; mi < 4; ++mi) {
      int r = wr * 64 + mi * 16 + l15;
      af[mi] = *(const f16x8*)((const char*)a_t + r * 80 + g4 * 16);
    }
#pragma unroll
    for (int ni = 0; ni < 4; ++ni) {
      int r = wc * 64 + ni * 16 + l15;
      bf[ni] = *(const f16x8*)((const char*)b_t + r * 64 + ((g4 * 16) ^ ((r & 3) << 4)));
    }
#pragma unroll
    for (int mi = 0; mi < 4; ++mi)
#pragma unroll
      for (int ni = 0; ni < 4; ++ni)
        acc[mi][ni] = __builtin_amdgcn_mfma_f32_16x16x32_f16(af[mi], bf[ni], acc[mi][ni], 0, 0, 0);
  }
#pragma unroll
  for (int mi = 0; mi < 4; ++mi)
#pragma unroll
    for (int ni = 0; ni < 4; ++ni)
#pragma unroll
      for (int di = 0; di < 4; ++di) {
        int row = Rbase + wr * 64 + mi * 16 + g4 * 4 + di;
        int col = Cbase + wc * 64 + ni * 16 + l15;
        float v = acc[mi][ni][di];
        Out[(size_t)row * 256 + col] = (f16)(v > 0.f ? v : 0.f);
      }
}

// ---- stage 1: 4-wave blocks share a double-buffered K tile; 1 barrier/tile.
// XCD-grouped linear grid (1024): the 16 blocks sharing each K slice sit on one XCD L2.
__global__ __launch_bounds__(256, 3) void sqk_kernel(
    const int* __restrict__ mask, const f16* __restrict__ Qh, const f16* __restrict__ Kh,
    f16* __restrict__ Sfrag, float2* __restrict__ Pstats) {
  const int bid = blockIdx.x;
  const int lb = (bid & 7) * 128 + (bid >> 3);   // bijective, 1024 = 8*128
  const int qgrp = lb & 15, g = lb >> 4;
  const int ms = g & 3, b = g >> 2;
  const int tid = threadIdx.x, lane = tid & 63, wave = tid >> 6;
  const int hi = lane >> 5, l31 = lane & 31;
  __shared__ f16 Kt[2][32 * 256];   // 2 x 16 KB, rows 512 B, XOR((m&31)<<4)

  const int qg = qgrp * 128 + wave * 32 + l31;
  f16x8 Qf[16];
  {
    const f16x8* qrow = (const f16x8*)(Qh + ((size_t)b * LL + qg) * HH);
#pragma unroll
    for (int c = 0; c < 16; ++c) Qf[c] = qrow[2 * c + hi];
  }
  const int* mrow = mask + b * LL;

  auto stageK = [&](int bufi, int mt) {
#pragma unroll
    for (int i = 0; i < 4; ++i) {
      int o = i * 4096 + tid * 16;
      int r = o >> 9, cp = o & 511;
      gload16((const char*)Kh + (size_t)(b * LL + mt * 32 + r) * 512 + (cp ^ ((r & 31) << 4)),
              (char*)Kt[bufi] + o);
    }
  };

  const int mt0 = ms * 16;
  stageK(0, mt0);
  __syncthreads();

  for (int i = 0; i < 16; ++i) {
    const int mt = mt0 + i;
    const int mbase = mt * 32;
    if (i) {
      asm volatile("s_waitcnt vmcnt(3)" ::: "memory");   // current-tile loads retired
      SCHED0(); BAR(); SCHED0();
    }
    stageK((i & 1) ^ 1, mt0 + ((i + 1) & 15));   // next tile (wrap harmless)

    const char* kb = (const char*)Kt[i & 1];
    f32x16 s0 = {}, s1 = {};
    __builtin_amdgcn_s_setprio(1);
#pragma unroll
    for (int c = 0; c < 8; ++c) {
      f16x8 kf0 = *(const f16x8*)(kb + l31 * 512 + (((2 * c) * 32 + hi * 16) ^ (l31 << 4)));
      f16x8 kf1 = *(const f16x8*)(kb + l31 * 512 + (((2 * c + 1) * 32 + hi * 16) ^ (l31 << 4)));
      s0 = __builtin_amdgcn_mfma_f32_32x32x16_f16(kf0, Qf[2 * c], s0, 0, 0, 0);
      s1 = __builtin_amdgcn_mfma_f32_32x32x16_f16(kf1, Qf[2 * c + 1], s1, 0, 0, 0);
    }
    __builtin_amdgcn_s_setprio(0);
    f32x16 s;
#pragma unroll
    for (int r = 0; r < 16; ++r) s[r] = s0[r] + s1[r];

    float tmax = MASKVAL;
#pragma unroll
    for (int c2 = 0; c2 < 4; ++c2) {
      int4 mk = *(const int4*)(mrow + mbase + c2 * 8 + hi * 4);
      float x;
      x = s[4*c2+0] * SCALE; s[4*c2+0] = mk.x ? x : MASKVAL;
      x = s[4*c2+1] * SCALE; s[4*c2+1] = mk.y ? x : MASKVAL;
      x = s[4*c2+2] * SCALE; s[4*c2+2] = mk.z ? x : MASKVAL;
      x = s[4*c2+3] * SCALE; s[4*c2+3] = mk.w ? x : MASKVAL;
      tmax = fmaxf(tmax, fmaxf(fmaxf(s[4*c2+0], s[4*c2+1]), fmaxf(s[4*c2+2], s[4*c2+3])));
    }
    tmax = fmaxf(tmax, __shfl_xor(tmax, 32, 64));
    float tsum = 0.f;
#pragma unroll
    for (int r = 0; r < 16; ++r) {
      float e = __expf(s[r] - tmax);
      s[r] = e;
      tsum += e;
    }
    tsum += __shfl_xor(tsum, 32, 64);

    f16x8 pf[2];
#pragma unroll
    for (int j = 0; j < 2; ++j) {
      unsigned a0 = pk2(s[8*j+0], s[8*j+1]);
      unsigned a1 = pk2(s[8*j+2], s[8*j+3]);
      unsigned b0 = pk2(s[8*j+4], s[8*j+5]);
      unsigned b1 = pk2(s[8*j+6], s[8*j+7]);
      asm volatile("v_permlane32_swap_b32 %0, %1" : "+v"(a0), "+v"(b0));
      asm volatile("v_permlane32_swap_b32 %0, %1" : "+v"(a1), "+v"(b1));
      union { f16x8 v; unsigned u[4]; } un;
      un.u[0] = a0; un.u[1] = a1; un.u[2] = b0; un.u[3] = b1;
      pf[j] = un.v;
    }
    const size_t mtg = (size_t)b * 64 + mt;
#pragma unroll
    for (int j = 0; j < 2; ++j)
      *(f16x8*)((char*)Sfrag + ((mtg * 2 + j) * 2048 + qg) * 32 + hi * 16) = pf[j];
    if (hi == 0) {
      float2 st; st.x = tmax; st.y = tsum;
      Pstats[mtg * 2048 + qg] = st;
    }
  }
}

// ---- stage 2: merge per-tile stats -> Mrow, Linv; concat-copy inputs -> out[...,512:]
__global__ void stats_copy_kernel(const float* __restrict__ X, const float2* __restrict__ Pstats,
                                  float* __restrict__ Mrow, float* __restrict__ Linv,
                                  float* __restrict__ out) {
  const int g = blockIdx.x, b = blockIdx.y;
  const int tid = threadIdx.x;
  const int row = g * 64 + (tid >> 2), sub = tid & 3;
  float bm[16], bs[16];
  float M = MASKVAL;
#pragma unroll
  for (int i = 0; i < 16; ++i) {
    float2 p = Pstats[((size_t)b * 64 + sub * 16 + i) * 2048 + row];
    bm[i] = p.x; bs[i] = p.y;
    M = fmaxf(M, p.x);
  }
  M = fmaxf(M, __shfl_xor(M, 1, 64));
  M = fmaxf(M, __shfl_xor(M, 2, 64));
  float L = 0.f;
#pragma unroll
  for (int i = 0; i < 16; ++i) L += bs[i] * __expf(bm[i] - M);
  L += __shfl_xor(L, 1, 64);
  L += __shfl_xor(L, 2, 64);
  if (sub == 0) {
    Mrow[(size_t)b * 2048 + row] = M;
    Linv[(size_t)b * 2048 + row] = 1.f / L;
  }
#pragma unroll
  for (int it = 0; it < 32; ++it) {
    int idx = it * 256 + tid;
    int r = idx >> 7, c4 = idx & 127;
    *(float4*)(out + ((size_t)b * 2048 + g * 64 + r) * 1024 + 512 + c4 * 4) =
        *(const float4*)(X + ((size_t)b * 2048 + g * 64 + r) * 512 + c4 * 4);
  }
}

// ---- stage 3: PV GEMM — BK=64 periods (2 m-tiles per barrier), T5 setprio.
// 512-thr blocks (8 waves = 4 qs x 2 dh), C[128q][256dv]/block, acc[4].
// Per period: vmcnt(6)+BAR, stage V-pair(p+1) [4 gloads -> 2x32KB ring],
// reg-load ps/pf for both next tiles [6], two 8-MFMA clusters (setprio-wrapped).
// Linear grid 512 = 8*64: XCD x serves 2 whole batches.
__global__ __launch_bounds__(512, 4) void pv_kernel(
    const f16* __restrict__ Sfrag, const float2* __restrict__ Pstats,
    const float* __restrict__ Mrow, const float* __restrict__ Linv,
    const f16* __restrict__ VT, float* __restrict__ out) {
  const int bid = blockIdx.x;
  const int lb = (bid & 7) * 64 + (bid >> 3);    // bijective, 512 = 8*64
  const int b = lb >> 5;
  const int rest = lb & 31;
  const int qt = rest & 15, dt = rest >> 4;
  const int tid = threadIdx.x, lane = tid & 63, wave = tid >> 6;
  const int hi = lane >> 5, l31 = lane & 31;
  const int qs = wave & 3, dh = wave >> 2;
  const int dvBase = dt * 256;
  const int qg = qt * 128 + qs * 32 + l31;
  __shared__ f16 Vt[2][2][256 * 32];   // ring[2] x slot[2] x 16 KB = 64 KB

  auto stage = [&](int bufi, int slot, int mt) {
#pragma unroll
    for (int i = 0; i < 2; ++i) {
      int o = i * 8192 + tid * 16;
      int dv = o >> 6, cp = o & 63;
      gload16((const char*)VT + (size_t)(b * 512 + dvBase + dv) * 4096 + mt * 64 + (cp ^ (((dv >> 1) & 3) << 4)),
              (char*)Vt[bufi][slot] + o);
    }
  };

  const float Mq = Mrow[(size_t)b * 2048 + qg];
  f32x16 acc[4] = {};

  auto compute = [&](float2 ps, f16x8 pf0, f16x8 pf1, const char* vb) {
    float fact = __expf(ps.x - Mq);    // exp(bmax - M); 0 for masked tiles
    f16 fh = (f16)fact;
    f16x8 fv = { fh, fh, fh, fh, fh, fh, fh, fh };
    f16x8 pA0 = pf0 * fv;
    f16x8 pA1 = pf1 * fv;
    __builtin_amdgcn_s_setprio(1);
#pragma unroll
    for (int dsub = 0; dsub < 4; ++dsub) {
      int dvl = dh * 128 + dsub * 32 + l31;
      f16x8 vf0 = *(const f16x8*)(vb + dvl * 64 + ((hi * 16) ^ (((dvl >> 1) & 3) << 4)));
      f16x8 vf1 = *(const f16x8*)(vb + dvl * 64 + ((32 + hi * 16) ^ (((dvl >> 1) & 3) << 4)));
      acc[dsub] = __builtin_amdgcn_mfma_f32_32x32x16_f16(pA0, vf0, acc[dsub], 0, 0, 0);
      acc[dsub] = __builtin_amdgcn_mfma_f32_32x32x16_f16(pA1, vf1, acc[dsub], 0, 0, 0);
    }
    __builtin_amdgcn_s_setprio(0);
  };

  // prologue: V tiles 0,1 + regs for tiles 0,1; single full drain
  stage(0, 0, 0);
  stage(0, 1, 1);
  const size_t gb = (size_t)b * 64;
  float2 ps_c0 = Pstats[(gb + 0) * 2048 + qg];
  f16x8 pf0_c0 = *(const f16x8*)((const char*)Sfrag + (((gb + 0) * 2 + 0) * 2048 + qg) * 32 + hi * 16);
  f16x8 pf1_c0 = *(const f16x8*)((const char*)Sfrag + (((gb + 0) * 2 + 1) * 2048 + qg) * 32 + hi * 16);
  float2 ps_c1 = Pstats[(gb + 1) * 2048 + qg];
  f16x8 pf0_c1 = *(const f16x8*)((const char*)Sfrag + (((gb + 1) * 2 + 0) * 2048 + qg) * 32 + hi * 16);
  f16x8 pf1_c1 = *(const f16x8*)((const char*)Sfrag + (((gb + 1) * 2 + 1) * 2048 + qg) * 32 + hi * 16);
  __syncthreads();

  for (int p = 0; p < 32; ++p) {
    if (p) {
      // retire this period's V-pair (4 oldest); last period's 6 reg loads newer —
      // they were consumed (compiler-waited) in the previous compute.
      asm volatile("s_waitcnt vmcnt(6)" ::: "memory");
      SCHED0(); BAR(); SCHED0();
    }
    const int n0 = (2 * p + 2) & 63, n1 = (2 * p + 3) & 63;
    stage((p + 1) & 1, 0, n0);
    stage((p + 1) & 1, 1, n1);
    const size_t g0 = gb + n0, g1 = gb + n1;
    float2 ps_n0 = Pstats[g0 * 2048 + qg];
    f16x8 pf0_n0 = *(const f16x8*)((const char*)Sfrag + ((g0 * 2 + 0) * 2048 + qg) * 32 + hi * 16);
    f16x8 pf1_n0 = *(const f16x8*)((const char*)Sfrag + ((g0 * 2 + 1) * 2048 + qg) * 32 + hi * 16);
    float2 ps_n1 = Pstats[g1 * 2048 + qg];
    f16x8 pf0_n1 = *(const f16x8*)((const char*)Sfrag + ((g1 * 2 + 0) * 2048 + qg) * 32 + hi * 16);
    f16x8 pf1_n1 = *(const f16x8*)((const char*)Sfrag + ((g1 * 2 + 1) * 2048 + qg) * 32 + hi * 16);

    compute(ps_c0, pf0_c0, pf1_c0, (const char*)Vt[p & 1][0]);
    compute(ps_c1, pf0_c1, pf1_c1, (const char*)Vt[p & 1][1]);

    ps_c0 = ps_n0; pf0_c0 = pf0_n0; pf1_c0 = pf1_n0;
    ps_c1 = ps_n1; pf0_c1 = pf0_n1; pf1_c1 = pf1_n1;
  }

  // epilogue: x 1/L per q-row, store C
  float linv = Linv[(size_t)b * 2048 + qg];
  float lr[16];
#pragma unroll
  for (int r = 0; r < 16; ++r) lr[r] = __shfl(linv, (r & 3) + 8 * (r >> 2) + 4 * hi, 32);
#pragma unroll
  for (int dsub = 0; dsub < 4; ++dsub) {
    int dv = dvBase + dh * 128 + dsub * 32 + l31;
#pragma unroll
    for (int r = 0; r < 16; ++r) {
      int q = qt * 128 + qs * 32 + (r & 3) + 8 * (r >> 2) + 4 * hi;
      out[((size_t)b * 2048 + q) * 1024 + dv] = acc[dsub][r] * lr[r];
    }
  }
}

extern "C" void kernel_launch(void* const* d_in, const int* in_sizes, int n_in,
                              void* d_out, int out_size, void* d_ws, size_t ws_size,
                              hipStream_t stream) {
  const float* inputs = (const float*)d_in[0];
  const float* memory = (const float*)d_in[1];
  const int*   mmask  = (const int*)d_in[2];
  const float* W_in   = (const float*)d_in[3];
  const float* W_mem  = (const float*)d_in[4];
  float* out = (float*)d_out;

  char* ws = (char*)d_ws;
  f16*    Qh     = (f16*)ws;                              // 16 MB
  f16*    Kh     = (f16*)(ws + (16ull << 20));            // 16 MB
  f16*    VT     = (f16*)(ws + (32ull << 20));            // 32 MB
  f16*    WTi    = (f16*)(ws + (64ull << 20));            // 256 KB
  f16*    WTm    = (f16*)(ws + (64ull << 20) + (1u << 18));
  f16*    Sfrag  = (f16*)(ws + (68ull << 20));            // 128 MB
  float2* Pstats = (float2*)(ws + (196ull << 20));        // 16 MB
  float*  MrowP  = (float*)(ws + (212ull << 20));         // 128 KB
  float*  LinvP  = (float*)(ws + (213ull << 20));         // 128 KB

  wt2_kernel<<<1024, 256, 0, stream>>>(W_in, W_mem, WTi, WTm);
  vt_kernel<<<dim3(64, 16, 16), 256, 0, stream>>>(memory, VT);
  proj_kernel<<<dim3(256, 2, 2), 256, 0, stream>>>(inputs, memory, WTi, WTm, Qh, Kh);
  sqk_kernel<<<1024, 256, 0, stream>>>(mmask, Qh, Kh, Sfrag, Pstats);
  stats_copy_kernel<<<dim3(32, 16), 256, 0, stream>>>(inputs, Pstats, MrowP, LinvP, out);
  pv_kernel<<<512, 512, 0, stream>>>(Sfrag, Pstats, MrowP, LinvP, VT, out);
}

// Round 16
// 278.178 us; speedup vs baseline: 1.0263x; 1.0263x over previous
//
#include <hip/hip_runtime.h>
#include <cstdint>
#include <cstddef>

typedef _Float16 f16;
typedef __attribute__((ext_vector_type(4)))  _Float16 f16x4;
typedef __attribute__((ext_vector_type(8)))  _Float16 f16x8;
typedef __attribute__((ext_vector_type(2)))  __fp16   fp16v2;
typedef __attribute__((ext_vector_type(4)))  float    f32x4;
typedef __attribute__((ext_vector_type(16))) float    f32x16;

static constexpr int BB = 16, LL = 2048, DIN = 512, HH = 256, DOUT = 1024;
static constexpr float SCALE = 0.0625f;   // 1/sqrt(256)
#define MASKVAL (-30000.0f)               // f16-representable; exp(-30000-M)=0 exactly

#define BAR()    __builtin_amdgcn_s_barrier()
#define SCHED0() __builtin_amdgcn_sched_barrier(0)

__device__ __forceinline__ void gload16(const void* g, void* l) {
  __builtin_amdgcn_global_load_lds(
      (const __attribute__((address_space(1))) unsigned int*)g,
      (__attribute__((address_space(3))) unsigned int*)l, 16, 0, 0);
}

__device__ __forceinline__ unsigned pk2(float a, float b) {
  union { fp16v2 v; unsigned u; } c;
  c.v = __builtin_amdgcn_cvt_pkrtz(a, b);
  return c.u;
}

// ---- both W transposes in one launch: W[512][256] f32 -> WT[256][512] f16
__global__ void wt2_kernel(const float* __restrict__ Wa, const float* __restrict__ Wb,
                           f16* __restrict__ WTa, f16* __restrict__ WTb) {
  int g = blockIdx.x * 256 + threadIdx.x;     // 262144 total
  const float* W = (g < 131072) ? Wa : Wb;
  f16* WT = (g < 131072) ? WTa : WTb;
  int gg = g & 131071;
  int d = gg >> 8, h = gg & 255;
  WT[h * 512 + d] = (f16)W[gg];
}

// ---- V transpose+cast: mem[b][m][512] f32 -> VT[b][512][2048] f16
__global__ void vt_kernel(const float* __restrict__ mem, f16* __restrict__ VT) {
  int m0 = blockIdx.x * 32, d0 = blockIdx.y * 32, b = blockIdx.z;
  __shared__ f16 t[32][36];
  int tid = threadIdx.x;
  {
    int r = tid >> 3, c4 = (tid & 7) * 4;
    float4 v = *(const float4*)(mem + (size_t)(b * LL + m0 + r) * DIN + d0 + c4);
    t[c4 + 0][r] = (f16)v.x; t[c4 + 1][r] = (f16)v.y;
    t[c4 + 2][r] = (f16)v.z; t[c4 + 3][r] = (f16)v.w;
  }
  __syncthreads();
  {
    int d = tid >> 3, seg = tid & 7;
    f16x4 hv = *(const f16x4*)&t[d][seg * 4];
    *(f16x4*)(VT + (size_t)(b * 512 + d0 + d) * 2048 + m0 + seg * 4) = hv;
  }
}

// ---- projection (both in one launch): Out[M][256] = f16(relu(X * W))
__global__ __launch_bounds__(256, 2) void proj_kernel(const float* __restrict__ Xa,
                                                      const float* __restrict__ Xb,
                                                      const f16* __restrict__ WTa,
                                                      const f16* __restrict__ WTb,
                                                      f16* __restrict__ Oa,
                                                      f16* __restrict__ Ob) {
  const float* X = blockIdx.z ? Xb : Xa;
  const f16* WT  = blockIdx.z ? WTb : WTa;
  f16* Out       = blockIdx.z ? Ob : Oa;
  const int Rbase = blockIdx.x * 128, Cbase = blockIdx.y * 128;
  __shared__ f16 a_t[128 * 40];
  __shared__ f16 b_t[128 * 32];
  const int tid = threadIdx.x, lane = tid & 63, wave = tid >> 6;
  const int wr = wave >> 1, wc = wave & 1;
  const int l15 = lane & 15, g4 = lane >> 4;
  f32x4 acc[4][4] = {};
  for (int ks = 0; ks < 16; ++ks) {
    __syncthreads();
#pragma unroll
    for (int k = 0; k < 4; ++k) {
      int idx = k * 256 + tid;
      int row = idx >> 3, c4 = idx & 7;
      float4 v = *(const float4*)(X + (size_t)(Rbase + row) * 512 + ks * 32 + c4 * 4);
      f16x4 hv = { (f16)v.x, (f16)v.y, (f16)v.z, (f16)v.w };
      *(f16x4*)((char*)a_t + row * 80 + c4 * 8) = hv;
    }
#pragma unroll
    for (int i = 0; i < 2; ++i) {
      int o = i * 4096 + wave * 1024 + lane * 16;
      int r = o >> 6, cp = o & 63;
      gload16((const char*)WT + (size_t)(Cbase + r) * 1024 + ks * 64 + (cp ^ ((r & 3) << 4)),
              (char*)b_t + i * 4096 + wave * 1024);
    }
    __syncthreads();
    f16x8 af[4], bf[4];
#pragma unroll
    for (int mi = 0; mi < 4; ++mi) {
      int r = wr * 64 + mi * 16 + l15;
      af[mi] = *(const f16x8*)((const char*)a_t + r * 80 + g4 * 16);
    }
#pragma unroll
    for (int ni = 0; ni < 4; ++ni) {
      int r = wc * 64 + ni * 16 + l15;
      bf[ni] = *(const f16x8*)((const char*)b_t + r * 64 + ((g4 * 16) ^ ((r & 3) << 4)));
    }
#pragma unroll
    for (int mi = 0; mi < 4; ++mi)
#pragma unroll
      for (int ni = 0; ni < 4; ++ni)
        acc[mi][ni] = __builtin_amdgcn_mfma_f32_16x16x32_f16(af[mi], bf[ni], acc[mi][ni], 0, 0, 0);
  }
#pragma unroll
  for (int mi = 0; mi < 4; ++mi)
#pragma unroll
    for (int ni = 0; ni < 4; ++ni)
#pragma unroll
      for (int di = 0; di < 4; ++di) {
        int row = Rbase + wr * 64 + mi * 16 + g4 * 4 + di;
        int col = Cbase + wc * 64 + ni * 16 + l15;
        float v = acc[mi][ni][di];
        Out[(size_t)row * 256 + col] = (f16)(v > 0.f ? v : 0.f);
      }
}

// ---- stage 1: 4-wave blocks share a double-buffered K tile; 1 barrier/tile.
// XCD-grouped linear grid (1024): the 16 blocks sharing each K slice sit on one XCD L2.
__global__ __launch_bounds__(256, 3) void sqk_kernel(
    const int* __restrict__ mask, const f16* __restrict__ Qh, const f16* __restrict__ Kh,
    f16* __restrict__ Sfrag, float2* __restrict__ Pstats) {
  const int bid = blockIdx.x;
  const int lb = (bid & 7) * 128 + (bid >> 3);   // bijective, 1024 = 8*128
  const int qgrp = lb & 15, g = lb >> 4;
  const int ms = g & 3, b = g >> 2;
  const int tid = threadIdx.x, lane = tid & 63, wave = tid >> 6;
  const int hi = lane >> 5, l31 = lane & 31;
  __shared__ f16 Kt[2][32 * 256];   // 2 x 16 KB, rows 512 B, XOR((m&31)<<4)

  const int qg = qgrp * 128 + wave * 32 + l31;
  f16x8 Qf[16];
  {
    const f16x8* qrow = (const f16x8*)(Qh + ((size_t)b * LL + qg) * HH);
#pragma unroll
    for (int c = 0; c < 16; ++c) Qf[c] = qrow[2 * c + hi];
  }
  const int* mrow = mask + b * LL;

  auto stageK = [&](int bufi, int mt) {
#pragma unroll
    for (int i = 0; i < 4; ++i) {
      int o = i * 4096 + tid * 16;
      int r = o >> 9, cp = o & 511;
      gload16((const char*)Kh + (size_t)(b * LL + mt * 32 + r) * 512 + (cp ^ ((r & 31) << 4)),
              (char*)Kt[bufi] + o);
    }
  };

  const int mt0 = ms * 16;
  stageK(0, mt0);
  __syncthreads();

  for (int i = 0; i < 16; ++i) {
    const int mt = mt0 + i;
    const int mbase = mt * 32;
    if (i) {
      asm volatile("s_waitcnt vmcnt(3)" ::: "memory");   // current-tile loads retired
      SCHED0(); BAR(); SCHED0();
    }
    stageK((i & 1) ^ 1, mt0 + ((i + 1) & 15));   // next tile (wrap harmless)

    const char* kb = (const char*)Kt[i & 1];
    f32x16 s0 = {}, s1 = {};
#pragma unroll
    for (int c = 0; c < 8; ++c) {
      f16x8 kf0 = *(const f16x8*)(kb + l31 * 512 + (((2 * c) * 32 + hi * 16) ^ (l31 << 4)));
      f16x8 kf1 = *(const f16x8*)(kb + l31 * 512 + (((2 * c + 1) * 32 + hi * 16) ^ (l31 << 4)));
      s0 = __builtin_amdgcn_mfma_f32_32x32x16_f16(kf0, Qf[2 * c], s0, 0, 0, 0);
      s1 = __builtin_amdgcn_mfma_f32_32x32x16_f16(kf1, Qf[2 * c + 1], s1, 0, 0, 0);
    }
    f32x16 s;
#pragma unroll
    for (int r = 0; r < 16; ++r) s[r] = s0[r] + s1[r];

    float tmax = MASKVAL;
#pragma unroll
    for (int c2 = 0; c2 < 4; ++c2) {
      int4 mk = *(const int4*)(mrow + mbase + c2 * 8 + hi * 4);
      float x;
      x = s[4*c2+0] * SCALE; s[4*c2+0] = mk.x ? x : MASKVAL;
      x = s[4*c2+1] * SCALE; s[4*c2+1] = mk.y ? x : MASKVAL;
      x = s[4*c2+2] * SCALE; s[4*c2+2] = mk.z ? x : MASKVAL;
      x = s[4*c2+3] * SCALE; s[4*c2+3] = mk.w ? x : MASKVAL;
      tmax = fmaxf(tmax, fmaxf(fmaxf(s[4*c2+0], s[4*c2+1]), fmaxf(s[4*c2+2], s[4*c2+3])));
    }
    tmax = fmaxf(tmax, __shfl_xor(tmax, 32, 64));
    float tsum = 0.f;
#pragma unroll
    for (int r = 0; r < 16; ++r) {
      float e = __expf(s[r] - tmax);
      s[r] = e;
      tsum += e;
    }
    tsum += __shfl_xor(tsum, 32, 64);

    f16x8 pf[2];
#pragma unroll
    for (int j = 0; j < 2; ++j) {
      unsigned a0 = pk2(s[8*j+0], s[8*j+1]);
      unsigned a1 = pk2(s[8*j+2], s[8*j+3]);
      unsigned b0 = pk2(s[8*j+4], s[8*j+5]);
      unsigned b1 = pk2(s[8*j+6], s[8*j+7]);
      asm volatile("v_permlane32_swap_b32 %0, %1" : "+v"(a0), "+v"(b0));
      asm volatile("v_permlane32_swap_b32 %0, %1" : "+v"(a1), "+v"(b1));
      union { f16x8 v; unsigned u[4]; } un;
      un.u[0] = a0; un.u[1] = a1; un.u[2] = b0; un.u[3] = b1;
      pf[j] = un.v;
    }
    const size_t mtg = (size_t)b * 64 + mt;
#pragma unroll
    for (int j = 0; j < 2; ++j)
      *(f16x8*)((char*)Sfrag + ((mtg * 2 + j) * 2048 + qg) * 32 + hi * 16) = pf[j];
    if (hi == 0) {
      float2 st; st.x = tmax; st.y = tsum;
      Pstats[mtg * 2048 + qg] = st;
    }
  }
}

// ---- stage 2: merge per-tile stats -> Mrow, Linv; concat-copy inputs -> out[...,512:]
__global__ void stats_copy_kernel(const float* __restrict__ X, const float2* __restrict__ Pstats,
                                  float* __restrict__ Mrow, float* __restrict__ Linv,
                                  float* __restrict__ out) {
  const int g = blockIdx.x, b = blockIdx.y;
  const int tid = threadIdx.x;
  const int row = g * 64 + (tid >> 2), sub = tid & 3;
  float bm[16], bs[16];
  float M = MASKVAL;
#pragma unroll
  for (int i = 0; i < 16; ++i) {
    float2 p = Pstats[((size_t)b * 64 + sub * 16 + i) * 2048 + row];
    bm[i] = p.x; bs[i] = p.y;
    M = fmaxf(M, p.x);
  }
  M = fmaxf(M, __shfl_xor(M, 1, 64));
  M = fmaxf(M, __shfl_xor(M, 2, 64));
  float L = 0.f;
#pragma unroll
  for (int i = 0; i < 16; ++i) L += bs[i] * __expf(bm[i] - M);
  L += __shfl_xor(L, 1, 64);
  L += __shfl_xor(L, 2, 64);
  if (sub == 0) {
    Mrow[(size_t)b * 2048 + row] = M;
    Linv[(size_t)b * 2048 + row] = 1.f / L;
  }
#pragma unroll
  for (int it = 0; it < 32; ++it) {
    int idx = it * 256 + tid;
    int r = idx >> 7, c4 = idx & 127;
    *(float4*)(out + ((size_t)b * 2048 + g * 64 + r) * 1024 + 512 + c4 * 4) =
        *(const float4*)(X + ((size_t)b * 2048 + g * 64 + r) * 512 + c4 * 4);
  }
}

// ---- stage 3: PV GEMM — R12 winner shape + XCD-bijective grid (R14 best).
// 512-thr blocks (8 waves = 4 qs x 2 dh), C[128q][256dv]/block, acc[4],
// software-pipelined operand prefetch, 1 barrier/iter, vmcnt(3).
// Linear grid 512 = 8*64: XCD x serves lb in [64x,64x+64) = 2 whole batches.
__global__ __launch_bounds__(512, 4) void pv_kernel(
    const f16* __restrict__ Sfrag, const float2* __restrict__ Pstats,
    const float* __restrict__ Mrow, const float* __restrict__ Linv,
    const f16* __restrict__ VT, float* __restrict__ out) {
  const int bid = blockIdx.x;
  const int lb = (bid & 7) * 64 + (bid >> 3);    // bijective, 512 = 8*64
  const int b = lb >> 5;
  const int rest = lb & 31;
  const int qt = rest & 15, dt = rest >> 4;
  const int tid = threadIdx.x, lane = tid & 63, wave = tid >> 6;
  const int hi = lane >> 5, l31 = lane & 31;
  const int qs = wave & 3, dh = wave >> 2;
  const int dvBase = dt * 256;
  const int qg = qt * 128 + qs * 32 + l31;
  __shared__ f16 Vt[2][256 * 32];   // 2 x 16 KB, rows 64 B, XOR(((dv>>1)&3)<<4)

  auto stage = [&](int bufi, int mt) {
#pragma unroll
    for (int i = 0; i < 2; ++i) {
      int o = i * 8192 + tid * 16;
      int dv = o >> 6, cp = o & 63;
      gload16((const char*)VT + (size_t)(b * 512 + dvBase + dv) * 4096 + mt * 64 + (cp ^ (((dv >> 1) & 3) << 4)),
              (char*)Vt[bufi] + o);
    }
  };

  const float Mq = Mrow[(size_t)b * 2048 + qg];
  f32x16 acc[4] = {};

  // prologue: V(0) + regs(0), single full drain
  stage(0, 0);
  const size_t mtg0 = (size_t)b * 64;
  float2 ps_c = Pstats[mtg0 * 2048 + qg];
  f16x8 pf0_c = *(const f16x8*)((const char*)Sfrag + ((mtg0 * 2 + 0) * 2048 + qg) * 32 + hi * 16);
  f16x8 pf1_c = *(const f16x8*)((const char*)Sfrag + ((mtg0 * 2 + 1) * 2048 + qg) * 32 + hi * 16);
  __syncthreads();

  for (int mt = 0; mt < 64; ++mt) {
    if (mt) {
      asm volatile("s_waitcnt vmcnt(3)" ::: "memory");   // V(mt) staged; regs(mt) keep flying
      SCHED0(); BAR(); SCHED0();
    }
    const int nmt = (mt + 1) & 63;
    stage((mt + 1) & 1, nmt);                    // 2 loads
    const size_t mtgn = (size_t)b * 64 + nmt;
    float2 ps_n = Pstats[mtgn * 2048 + qg];
    f16x8 pf0_n = *(const f16x8*)((const char*)Sfrag + ((mtgn * 2 + 0) * 2048 + qg) * 32 + hi * 16);
    f16x8 pf1_n = *(const f16x8*)((const char*)Sfrag + ((mtgn * 2 + 1) * 2048 + qg) * 32 + hi * 16);

    float fact = __expf(ps_c.x - Mq);            // exp(bmax - M); 0 for masked tiles
    f16 fh = (f16)fact;
    f16x8 fv = { fh, fh, fh, fh, fh, fh, fh, fh };
    f16x8 pA0 = pf0_c * fv;
    f16x8 pA1 = pf1_c * fv;

    const char* vb = (const char*)Vt[mt & 1];
#pragma unroll
    for (int dsub = 0; dsub < 4; ++dsub) {
      int dvl = dh * 128 + dsub * 32 + l31;
      f16x8 vf0 = *(const f16x8*)(vb + dvl * 64 + ((hi * 16) ^ (((dvl >> 1) & 3) << 4)));
      f16x8 vf1 = *(const f16x8*)(vb + dvl * 64 + ((32 + hi * 16) ^ (((dvl >> 1) & 3) << 4)));
      acc[dsub] = __builtin_amdgcn_mfma_f32_32x32x16_f16(pA0, vf0, acc[dsub], 0, 0, 0);
      acc[dsub] = __builtin_amdgcn_mfma_f32_32x32x16_f16(pA1, vf1, acc[dsub], 0, 0, 0);
    }
    ps_c = ps_n; pf0_c = pf0_n; pf1_c = pf1_n;
  }

  // epilogue: x 1/L per q-row, store C
  float linv = Linv[(size_t)b * 2048 + qg];
  float lr[16];
#pragma unroll
  for (int r = 0; r < 16; ++r) lr[r] = __shfl(linv, (r & 3) + 8 * (r >> 2) + 4 * hi, 32);
#pragma unroll
  for (int dsub = 0; dsub < 4; ++dsub) {
    int dv = dvBase + dh * 128 + dsub * 32 + l31;
#pragma unroll
    for (int r = 0; r < 16; ++r) {
      int q = qt * 128 + qs * 32 + (r & 3) + 8 * (r >> 2) + 4 * hi;
      out[((size_t)b * 2048 + q) * 1024 + dv] = acc[dsub][r] * lr[r];
    }
  }
}

extern "C" void kernel_launch(void* const* d_in, const int* in_sizes, int n_in,
                              void* d_out, int out_size, void* d_ws, size_t ws_size,
                              hipStream_t stream) {
  const float* inputs = (const float*)d_in[0];
  const float* memory = (const float*)d_in[1];
  const int*   mmask  = (const int*)d_in[2];
  const float* W_in   = (const float*)d_in[3];
  const float* W_mem  = (const float*)d_in[4];
  float* out = (float*)d_out;

  char* ws = (char*)d_ws;
  f16*    Qh     = (f16*)ws;                              // 16 MB
  f16*    Kh     = (f16*)(ws + (16ull << 20));            // 16 MB
  f16*    VT     = (f16*)(ws + (32ull << 20));            // 32 MB
  f16*    WTi    = (f16*)(ws + (64ull << 20));            // 256 KB
  f16*    WTm    = (f16*)(ws + (64ull << 20) + (1u << 18));
  f16*    Sfrag  = (f16*)(ws + (68ull << 20));            // 128 MB
  float2* Pstats = (float2*)(ws + (196ull << 20));        // 16 MB
  float*  MrowP  = (float*)(ws + (212ull << 20));         // 128 KB
  float*  LinvP  = (float*)(ws + (213ull << 20));         // 128 KB

  wt2_kernel<<<1024, 256, 0, stream>>>(W_in, W_mem, WTi, WTm);
  vt_kernel<<<dim3(64, 16, 16), 256, 0, stream>>>(memory, VT);
  proj_kernel<<<dim3(256, 2, 2), 256, 0, stream>>>(inputs, memory, WTi, WTm, Qh, Kh);
  sqk_kernel<<<1024, 256, 0, stream>>>(mmask, Qh, Kh, Sfrag, Pstats);
  stats_copy_kernel<<<dim3(32, 16), 256, 0, stream>>>(inputs, Pstats, MrowP, LinvP, out);
  pv_kernel<<<512, 512, 0, stream>>>(Sfrag, Pstats, MrowP, LinvP, VT, out);
}